// Round 1
// baseline (202.691 us; speedup 1.0000x reference)
//
#include <hip/hip_runtime.h>

#define SCALE 0.17677669529663687f  // 1/sqrt(32)

// ---------------------------------------------------------------------------
// One block per query row i. 512 blocks x 1024 thr (16 waves) -> 32 waves/CU.
//
// Prologue: q_s = (x[i]@Wq)*SCALE;
//   s_qc[c*16+h]   = sum_d q_s[h*32+d]*We[c*256+h*32+d]   (e-coef)
//   s_qc[c*16+8+h] = sum_d q_s[h*32+d]*Wk[c*256+h*32+d]   (x-coef)
// P1 (thread = (j, head-half)): acc[4] logits in registers
// P2: in-register softmax: wave butterfly max/sum + s_red cross-wave combine;
//     write UNNORMALIZED probs transposed s_pt[j][h]; 1/sum kept in s_inv
// P3 (lane=c, wave owns 32 j): ae/px partials -> LDS atomicAdd
// Normalize by s_inv, then epilogue GEMMs (scratch aliased into s_pt).
// ---------------------------------------------------------------------------
__global__ __launch_bounds__(1024, 8) void fused_kernel(
    const float* __restrict__ e, const float* __restrict__ x,
    const float* __restrict__ Wq, const float* __restrict__ Wk,
    const float* __restrict__ We, const float* __restrict__ Wv,
    const float* __restrict__ Wo, const float* __restrict__ bo,
    float* __restrict__ out) {
  const int t = threadIdx.x, i = blockIdx.x;
  const int lane = t & 63, w = t >> 6;   // wave 0..15
  const int j = t & 511;                 // phase-1/2 row index
  const int hb = (t >> 9) * 4;           // head base: 0 or 4

  __shared__ float s_x[64];
  __shared__ __align__(16) float s_q[256];
  __shared__ __align__(16) float s_qc[1024];   //  4 KB coefs
  __shared__ __align__(16) float s_pt[4096];   // 16 KB probs [j][h]; epilogue scratch later
  __shared__ __align__(16) float s_red[64];    // per-wave max partials
  __shared__ __align__(16) float s_red2[64];   // per-wave sum partials
  __shared__ float s_inv[8];
  __shared__ __align__(16) float s_ae[512];
  __shared__ __align__(16) float s_px[512];

  // ---- init + prologue
  if (t < 512) { s_ae[t] = 0.f; s_px[t] = 0.f; }
  if (t < 64) s_x[t] = x[i * 64 + t];
  __syncthreads();
  if (t < 256) {
    float a = 0;
#pragma unroll 8
    for (int c = 0; c < 64; ++c) a += s_x[c] * Wq[c * 256 + t];
    s_q[t] = a * SCALE;
  }
  __syncthreads();
  {  // coefficients: 1024 threads = 64 c x {We,Wk} x 8 h
    const int c = t >> 4, hv = t & 15, which = hv >> 3, h = hv & 7;
    const float* W = which ? Wk : We;
    const float4* wr = (const float4*)(W + c * 256 + h * 32);
    const float4* qr = (const float4*)(s_q + h * 32);
    float s = 0;
#pragma unroll
    for (int u = 0; u < 8; ++u) {
      float4 wv4 = wr[u], qv = qr[u];
      s += qv.x * wv4.x + qv.y * wv4.y + qv.z * wv4.z + qv.w * wv4.w;
    }
    s_qc[c * 16 + which * 8 + h] = s;
  }
  __syncthreads();

  // ---- Phase 1: logits for (j, heads hb..hb+3) in registers
  float acc[4];
  {
    const float4* erow = (const float4*)(e + (size_t)(i * 512 + j) * 64);
    const float4* xrow = (const float4*)(x + j * 64);
    acc[0] = acc[1] = acc[2] = acc[3] = 0.f;
#pragma unroll 4
    for (int c4 = 0; c4 < 16; ++c4) {
      float4 E = erow[c4];
      float4 X = xrow[c4];
      const float* qc = s_qc + c4 * 64 + hb;  // wave-uniform LDS broadcast
#pragma unroll
      for (int hh = 0; hh < 4; ++hh) {
        acc[hh] += E.x * qc[hh]      + E.y * qc[16 + hh]
                 + E.z * qc[32 + hh] + E.w * qc[48 + hh]
                 + X.x * qc[8 + hh]  + X.y * qc[24 + hh]
                 + X.z * qc[40 + hh] + X.w * qc[56 + hh];
      }
    }
  }

  // ---- Phase 2a: per-wave (64 j) max for this thread's 4 heads
  {
#pragma unroll
    for (int hh = 0; hh < 4; ++hh) {
      float m = acc[hh];
#pragma unroll
      for (int off = 32; off; off >>= 1) m = fmaxf(m, __shfl_xor(m, off, 64));
      if (lane == 0) s_red[w * 4 + hh] = m;
    }
  }
  __syncthreads();
  // ---- Phase 2b: global max, exp in place, write unnormalized probs, wave sums
  {
    const int half8 = (t >> 9) * 8;  // quads 0..7 = heads 0-3 (waves 0-7), 8..15 = heads 4-7
    float4 M = ((const float4*)s_red)[half8];
#pragma unroll
    for (int ww = 1; ww < 8; ++ww) {
      float4 a = ((const float4*)s_red)[half8 + ww];
      M.x = fmaxf(M.x, a.x); M.y = fmaxf(M.y, a.y);
      M.z = fmaxf(M.z, a.z); M.w = fmaxf(M.w, a.w);
    }
    acc[0] = __expf(acc[0] - M.x);
    acc[1] = __expf(acc[1] - M.y);
    acc[2] = __expf(acc[2] - M.z);
    acc[3] = __expf(acc[3] - M.w);
    *(float4*)(s_pt + j * 8 + hb) = make_float4(acc[0], acc[1], acc[2], acc[3]);
#pragma unroll
    for (int hh = 0; hh < 4; ++hh) {
      float s = acc[hh];
#pragma unroll
      for (int off = 32; off; off >>= 1) s += __shfl_xor(s, off, 64);
      if (lane == 0) s_red2[w * 4 + hh] = s;
    }
  }
  __syncthreads();
  if (t < 8) {  // 1/denominator per head
    const int half32 = (t >> 2) * 32, hh = t & 3;
    float s = 0;
#pragma unroll
    for (int ww = 0; ww < 8; ++ww) s += s_red2[half32 + ww * 4 + hh];
    s_inv[t] = 1.0f / s;
  }

  // ---- Phase 3: lane=c, wave w owns j in [w*32, w*32+32)
  {
    float ae[8], px[8];
#pragma unroll
    for (int h = 0; h < 8; ++h) { ae[h] = 0.f; px[h] = 0.f; }
    const float* ep = e + (size_t)i * 32768 + w * 2048 + lane;
    const float* xp = x + w * 2048 + lane;
#pragma unroll 4
    for (int jj = 0; jj < 32; ++jj) {
      float ev = ep[jj * 64];  // coalesced 256B/wave
      float xv = xp[jj * 64];
      const float4* pt = (const float4*)(s_pt + (w * 32 + jj) * 8);  // uniform broadcast
      float4 p0 = pt[0], p1 = pt[1];
      ae[0] += p0.x * ev; ae[1] += p0.y * ev; ae[2] += p0.z * ev; ae[3] += p0.w * ev;
      ae[4] += p1.x * ev; ae[5] += p1.y * ev; ae[6] += p1.z * ev; ae[7] += p1.w * ev;
      px[0] += p0.x * xv; px[1] += p0.y * xv; px[2] += p0.z * xv; px[3] += p0.w * xv;
      px[4] += p1.x * xv; px[5] += p1.y * xv; px[6] += p1.z * xv; px[7] += p1.w * xv;
    }
#pragma unroll
    for (int h = 0; h < 8; ++h) {
      atomicAdd(&s_ae[h * 64 + lane], ae[h]);  // ds_add_f32, 2-way bank spread (free)
      atomicAdd(&s_px[h * 64 + lane], px[h]);
    }
  }
  __syncthreads();

  // ---- fold in softmax normalization
  if (t < 512) {
    s_ae[t] *= s_inv[t >> 6];
  } else {
    const int t2 = t - 512;
    s_px[t2] *= s_inv[t2 >> 6];
  }
  __syncthreads();

  // ---- Epilogue (scratch aliases the now-dead s_pt)
  float* s_eb  = s_pt;         // 1024 floats: partial emb
  float* s_emb = s_pt + 1024;  // 256 floats
  float* s_op  = s_pt + 1280;  // 1024 floats
  {
    const int nd = t & 255, ch = t >> 8, hn = nd >> 5;
    float emb = 0;
    const int cb = ch * 16;
#pragma unroll
    for (int c = cb; c < cb + 16; ++c)
      emb += s_ae[hn * 64 + c] * We[c * 256 + nd] + s_px[hn * 64 + c] * Wv[c * 256 + nd];
    s_eb[ch * 256 + nd] = emb;
  }
  __syncthreads();
  if (t < 256) s_emb[t] = s_eb[t] + s_eb[256 + t] + s_eb[512 + t] + s_eb[768 + t];
  __syncthreads();
  {
    const int o = t & 63, mc = t >> 6;
    float oo = 0;
#pragma unroll
    for (int m2 = mc * 16; m2 < mc * 16 + 16; ++m2) oo += s_emb[m2] * Wo[m2 * 64 + o];
    s_op[mc * 64 + o] = oo;
  }
  __syncthreads();
  if (t < 64) {
    float r = bo[t];
#pragma unroll
    for (int w2 = 0; w2 < 16; ++w2) r += s_op[w2 * 64 + t];
    out[i * 64 + t] = r;
  }
}

extern "C" void kernel_launch(void* const* d_in, const int* in_sizes, int n_in,
                              void* d_out, int out_size, void* d_ws, size_t ws_size,
                              hipStream_t stream) {
  const float* x  = (const float*)d_in[0];
  const float* e  = (const float*)d_in[1];
  const float* Wq = (const float*)d_in[2];
  const float* Wk = (const float*)d_in[3];
  const float* Wv = (const float*)d_in[4];
  const float* We = (const float*)d_in[5];
  const float* Wo = (const float*)d_in[6];
  const float* bo = (const float*)d_in[7];
  float* out = (float*)d_out;

  hipLaunchKernelGGL(fused_kernel, dim3(512), dim3(1024), 0, stream,
                     e, x, Wq, Wk, We, Wv, Wo, bo, out);
}